// Round 1
// baseline (660.269 us; speedup 1.0000x reference)
//
#include <hip/hip_runtime.h>
#include <hip/hip_bf16.h>

// L21 norm: out = sum_c sqrt(sum_r S[r,c]^2), S is fp32 [8192, 16384] row-major.
// Memory-bound streaming reduction: 512 MiB read, roofline ~85 us at 6.3 TB/s.

#define N_ROWS 8192
#define N_COLS 16384
#define CHUNKS 32                      // row chunks -> 32*16 = 512 blocks in kernel 1
#define ROWS_PER_CHUNK (N_ROWS / CHUNKS)
#define THREADS 256
#define COLS_PER_BLOCK (THREADS * 4)   // float4 per thread -> 1024 cols/block

// Kernel 1: per-(chunk, column) partial sum of squares -> ws[chunk*N_COLS + col]
__global__ __launch_bounds__(THREADS) void l21_partial_kernel(
    const float* __restrict__ S, float* __restrict__ partial) {
    const int col4 = blockIdx.x * COLS_PER_BLOCK + threadIdx.x * 4;  // first of 4 cols
    const int r0   = blockIdx.y * ROWS_PER_CHUNK;

    const float4* p = (const float4*)(S + (size_t)r0 * N_COLS + col4);
    float4 acc = make_float4(0.f, 0.f, 0.f, 0.f);
#pragma unroll 8
    for (int r = 0; r < ROWS_PER_CHUNK; ++r) {
        float4 v = p[(size_t)r * (N_COLS / 4)];
        acc.x += v.x * v.x;
        acc.y += v.y * v.y;
        acc.z += v.z * v.z;
        acc.w += v.w * v.w;
    }
    *(float4*)(partial + (size_t)blockIdx.y * N_COLS + col4) = acc;
}

// Kernel 2: per column sum the CHUNKS partials, sqrt, reduce to scalar.
// 64 blocks x 256 threads: one thread per column.
__global__ __launch_bounds__(THREADS) void l21_finish_kernel(
    const float* __restrict__ partial, float* __restrict__ out) {
    const int col = blockIdx.x * THREADS + threadIdx.x;

    float s = 0.f;
#pragma unroll
    for (int c = 0; c < CHUNKS; ++c)
        s += partial[(size_t)c * N_COLS + col];  // coalesced across threads
    float v = sqrtf(s);

    // wave-64 shuffle reduction
#pragma unroll
    for (int off = 32; off > 0; off >>= 1)
        v += __shfl_down(v, off, 64);

    __shared__ float wsum[THREADS / 64];
    const int lane = threadIdx.x & 63;
    const int wave = threadIdx.x >> 6;
    if (lane == 0) wsum[wave] = v;
    __syncthreads();

    if (threadIdx.x == 0) {
        float t = 0.f;
#pragma unroll
        for (int w = 0; w < THREADS / 64; ++w) t += wsum[w];
        atomicAdd(out, t);  // 64 blocks, device-scope default
    }
}

extern "C" void kernel_launch(void* const* d_in, const int* in_sizes, int n_in,
                              void* d_out, int out_size, void* d_ws, size_t ws_size,
                              hipStream_t stream) {
    const float* S = (const float*)d_in[0];
    float* out     = (float*)d_out;
    float* partial = (float*)d_ws;  // needs CHUNKS * N_COLS * 4 = 2 MiB

    // d_out is poisoned 0xAA before every timed launch -> zero it (capture-safe).
    hipMemsetAsync(out, 0, sizeof(float), stream);

    dim3 grid1(N_COLS / COLS_PER_BLOCK, CHUNKS);  // (16, 32) = 512 blocks
    l21_partial_kernel<<<grid1, THREADS, 0, stream>>>(S, partial);

    dim3 grid2(N_COLS / THREADS);  // 64 blocks
    l21_finish_kernel<<<grid2, THREADS, 0, stream>>>(partial, out);
}